// Round 3
// baseline (1305.173 us; speedup 1.0000x reference)
//
#include <hip/hip_runtime.h>
#include <stdint.h>

typedef unsigned short u16;

#define B_   2
#define S_   2048
#define H_   4096
#define NH   32
#define NKV  8
#define HD   128
#define KVD  (NKV * HD)   // 1024
#define BS   (B_ * S_)    // 4096

typedef __bf16 bf16x8 __attribute__((ext_vector_type(8)));
typedef u16    u16x8  __attribute__((ext_vector_type(8)));
typedef u16    u16x4  __attribute__((ext_vector_type(4)));
typedef float  f32x4  __attribute__((ext_vector_type(4)));

__device__ __forceinline__ bf16x8 as_bf16x8(u16x8 v) { return __builtin_bit_cast(bf16x8, v); }

__device__ __forceinline__ float bf2f(u16 u) {
  union { uint32_t u; float f; } v; v.u = ((uint32_t)u) << 16; return v.f;
}
__device__ __forceinline__ u16 f2bf(float f) {
  union { float f; uint32_t u; } v; v.f = f;
  uint32_t r = v.u + 0x7FFFu + ((v.u >> 16) & 1u);
  return (u16)(r >> 16);
}

// async global->LDS, 16B per lane; LDS dest must be wave-uniform-base + lane*16
__device__ __forceinline__ void gload_lds16(const void* g, void* l) {
  __builtin_amdgcn_global_load_lds((const __attribute__((address_space(1))) void*)g,
                                   (__attribute__((address_space(3))) void*)l, 16, 0, 0);
}

// ---------------------------------------------------------------------------
// fp32 -> bf16 elementwise (vectorized, 8 elems/thread)
// ---------------------------------------------------------------------------
__global__ __launch_bounds__(256) void conv_bf16(const float* __restrict__ in,
                                                 u16* __restrict__ out) {
  size_t i = ((size_t)blockIdx.x * 256 + threadIdx.x) * 8;
  float4 a = *(const float4*)(in + i);
  float4 b = *(const float4*)(in + i + 4);
  u16x8 h;
  h[0] = f2bf(a.x); h[1] = f2bf(a.y); h[2] = f2bf(a.z); h[3] = f2bf(a.w);
  h[4] = f2bf(b.x); h[5] = f2bf(b.y); h[6] = f2bf(b.z); h[7] = f2bf(b.w);
  *(u16x8*)(out + i) = h;
}

// ---------------------------------------------------------------------------
// Convert + transpose: fp32 in[R][C] -> bf16 out[C][R]; 64x64 tiles.
// ---------------------------------------------------------------------------
__global__ __launch_bounds__(256) void conv_transpose_w(const float* __restrict__ in,
                                                        u16* __restrict__ out,
                                                        int ldi, int ldo) {
  __shared__ u16 tile[64][72];
  int r0 = blockIdx.x * 64, c0 = blockIdx.y * 64;
  int t = threadIdx.x;
  {
    int row = t >> 4, col = (t & 15) * 4;
#pragma unroll
    for (int rep = 0; rep < 4; ++rep) {
      int r = row + rep * 16;
      float4 v = *(const float4*)(in + (size_t)(r0 + r) * ldi + c0 + col);
      u16x4 h;
      h[0] = f2bf(v.x); h[1] = f2bf(v.y); h[2] = f2bf(v.z); h[3] = f2bf(v.w);
      *(u16x4*)&tile[r][col] = h;
    }
  }
  __syncthreads();
  {
    int row = t >> 2, c8 = (t & 3) * 8;
#pragma unroll
    for (int it = 0; it < 2; ++it) {
      int rr = c8 + it * 32;
      u16x8 v;
#pragma unroll
      for (int j = 0; j < 8; ++j) v[j] = tile[rr + j][row];
      *(u16x8*)(out + (size_t)(c0 + row) * ldo + r0 + rr) = v;
    }
  }
}

// ---------------------------------------------------------------------------
// V transpose (bf16): V[b*S_+s][kvh*HD+d] -> Vt[((b*NKV+kvh)*HD + d)*S_ + s]
// ---------------------------------------------------------------------------
__global__ __launch_bounds__(256) void transpose_v(const u16* __restrict__ V,
                                                   u16* __restrict__ Vt) {
  __shared__ u16 tile[64][72];
  int g = blockIdx.z;
  const u16* in = V + (size_t)(g >> 3) * ((size_t)S_ * KVD) + (size_t)(g & 7) * HD;
  u16* out = Vt + (size_t)g * ((size_t)HD * S_);
  int r0 = blockIdx.x * 64, c0 = blockIdx.y * 64;
  int t = threadIdx.x;
  int row = t >> 2, c8 = (t & 3) * 8;
#pragma unroll
  for (int it = 0; it < 2; ++it) {
    int col = c8 + it * 32;
    *(u16x8*)&tile[row][col] = *(const u16x8*)(in + (size_t)(r0 + row) * KVD + c0 + col);
  }
  __syncthreads();
#pragma unroll
  for (int it = 0; it < 2; ++it) {
    int rr = c8 + it * 32;
    u16x8 v;
#pragma unroll
    for (int j = 0; j < 8; ++j) v[j] = tile[rr + j][row];
    *(u16x8*)(out + (size_t)(c0 + row) * S_ + r0 + rr) = v;
  }
}

// ---------------------------------------------------------------------------
// C[M][N] = A[M][K] @ Bt[N][K]^T.  A bf16, C bf16 or fp32.
// m97 structure: 128x128 tile, BK=32, global_load_lds dwordx4 staging,
// 4 waves of 64x64, 16x16x32 bf16 MFMA.
// ---------------------------------------------------------------------------
template <bool C_F32>
__global__ __launch_bounds__(256) void gemm_bt_lds(const u16* __restrict__ A,
                                                   const u16* __restrict__ Bt,
                                                   void* __restrict__ Cp,
                                                   int M, int N, int K) {
  __shared__ __align__(16) u16 lsA[128][32];
  __shared__ __align__(16) u16 lsB[128][32];
  int t = threadIdx.x;
  int lane = t & 63;
  int w = t >> 6;
  int wm = (w >> 1) * 64, wn = (w & 1) * 64;
  int bm = blockIdx.x * 128, bn = blockIdx.y * 128;
  int fr = lane & 15, kq = lane >> 4;
  f32x4 acc[4][4] = {};

  int sr = t >> 2, sc = (t & 3) * 8;
  const u16* Ar0 = A + (size_t)(bm + sr) * K + sc;
  const u16* Ar1 = A + (size_t)(bm + sr + 64) * K + sc;
  const u16* Br0 = Bt + (size_t)(bn + sr) * K + sc;
  const u16* Br1 = Bt + (size_t)(bn + sr + 64) * K + sc;
  u16* lA0 = &lsA[sr][sc];
  u16* lA1 = &lsA[sr + 64][sc];
  u16* lB0 = &lsB[sr][sc];
  u16* lB1 = &lsB[sr + 64][sc];

  for (int k0 = 0; k0 < K; k0 += 32) {
    gload_lds16(Ar0 + k0, lA0);
    gload_lds16(Ar1 + k0, lA1);
    gload_lds16(Br0 + k0, lB0);
    gload_lds16(Br1 + k0, lB1);
    __syncthreads();  // drains vmcnt(0): LDS tiles complete
    bf16x8 af[4], bfr[4];
#pragma unroll
    for (int i = 0; i < 4; ++i) af[i] = as_bf16x8(*(const u16x8*)&lsA[wm + i * 16 + fr][kq * 8]);
#pragma unroll
    for (int j = 0; j < 4; ++j) bfr[j] = as_bf16x8(*(const u16x8*)&lsB[wn + j * 16 + fr][kq * 8]);
#pragma unroll
    for (int i = 0; i < 4; ++i)
#pragma unroll
      for (int j = 0; j < 4; ++j)
        acc[i][j] = __builtin_amdgcn_mfma_f32_16x16x32_bf16(af[i], bfr[j], acc[i][j], 0, 0, 0);
    __syncthreads();  // protect LDS from next-iter staging
  }
#pragma unroll
  for (int i = 0; i < 4; ++i)
#pragma unroll
    for (int j = 0; j < 4; ++j)
#pragma unroll
      for (int r = 0; r < 4; ++r) {
        int row = bm + wm + i * 16 + kq * 4 + r;
        int col = bn + wn + j * 16 + fr;
        if (C_F32) ((float*)Cp)[(size_t)row * N + col] = acc[i][j][r];
        else       ((u16*)Cp)[(size_t)row * N + col] = f2bf(acc[i][j][r]);
      }
}

// ---------------------------------------------------------------------------
// RoPE in-place on bf16 Q [BS][H_] and K [BS][KVD].
// ---------------------------------------------------------------------------
__global__ __launch_bounds__(256) void rope_kernel(u16* __restrict__ Q,
                                                   u16* __restrict__ Kp) {
  int idx = blockIdx.x * 256 + threadIdx.x;  // BS * 40 * 64 total
  int j = idx & 63;
  int rem = idx >> 6;
  int hh = rem % 40;
  int tok = rem / 40;
  float p = (float)(tok % S_);
  float freq = __expf((float)j * (-9.210340371976184f / 64.0f));  // 10000^(-j/64)
  float sn, cs;
  __sincosf(p * freq, &sn, &cs);
  u16* base = (hh < NH) ? (Q + (size_t)tok * H_ + (size_t)hh * HD)
                        : (Kp + (size_t)tok * KVD + (size_t)(hh - NH) * HD);
  float x1 = bf2f(base[j]), x2 = bf2f(base[j + 64]);
  base[j]      = f2bf(x1 * cs - x2 * sn);
  base[j + 64] = f2bf(x2 * cs + x1 * sn);
}

// ---------------------------------------------------------------------------
// Flash attention, causal, GQA(4) — v3: NO K/V LDS staging, no barriers.
// K+V per (b,kvh) group = 1 MB; blocks of a group pinned to one XCD
// (bid%8 == kvh), so per-XCD L2 working set = 2 groups = 2 MB <= 4 MB.
// Each wave reads its K/V MFMA fragments directly from global (L2-served);
// latency hidden by TLP (no barriers, ~16 waves/CU vs 4.6 effective before).
// grid: 1D, 2048 blocks = 128 qt x 16 groups; qt longest-first.
// 4 waves/block = the 4 heads of the GQA group; 16 q-rows per wave.
// ---------------------------------------------------------------------------
__global__ __launch_bounds__(256) void flash_attn(const u16* __restrict__ Q,
                                                  const u16* __restrict__ Kp,
                                                  const u16* __restrict__ Vt,
                                                  u16* __restrict__ O) {
  __shared__ u16 Plds[4][16][72];              // per-wave P tile, +8 pad
  int bid = blockIdx.x;
  int g = bid & 15;                            // group; bid%8 == kvh -> XCD pin
  int kvh = g & 7, b = g >> 3;
  int qt = (S_ / 16 - 1) - (bid >> 4);         // longest blocks first
  int t = threadIdx.x, lane = t & 63, w = t >> 6;
  int h = kvh * 4 + w;                         // this wave's head
  int fr = lane & 15, kq = lane >> 4;
  int q0 = qt * 16;

  const u16* qbase = Q + (size_t)(b * S_ + q0 + fr) * H_ + (size_t)h * HD;
  bf16x8 qf[4];
#pragma unroll
  for (int kk = 0; kk < 4; ++kk) qf[kk] = as_bf16x8(*(const u16x8*)(qbase + kk * 32 + kq * 8));

  f32x4 o[8] = {};
  float mrow[4] = {-1e30f, -1e30f, -1e30f, -1e30f};
  float lrow[4] = {0.f, 0.f, 0.f, 0.f};

  const u16* kbase = Kp + (size_t)(b * S_) * KVD + (size_t)kvh * HD;
  const u16* vbase = Vt + (size_t)(b * NKV + kvh) * ((size_t)HD * S_);
  const float scale = 0.08838834764831845f;  // 1/sqrt(128)

  int niter = (q0 + 15) / 64 + 1;
  for (int kt = 0; kt < niter; ++kt) {
    int k0 = kt * 64;

    // ---- S = Q K^T, K fragments straight from global (L2)
    f32x4 s[4] = {};
#pragma unroll
    for (int kk = 0; kk < 4; ++kk) {
#pragma unroll
      for (int j = 0; j < 4; ++j) {
        bf16x8 kf = as_bf16x8(*(const u16x8*)(kbase + (size_t)(k0 + j * 16 + fr) * KVD + (kk * 4 + kq) * 8));
        s[j] = __builtin_amdgcn_mfma_f32_16x16x32_bf16(qf[kk], kf, s[j], 0, 0, 0);
      }
    }
    // ---- scale + causal mask + row max
    float mt[4] = {-1e30f, -1e30f, -1e30f, -1e30f};
#pragma unroll
    for (int j = 0; j < 4; ++j) {
      int kv = k0 + j * 16 + fr;
#pragma unroll
      for (int r = 0; r < 4; ++r) {
        int qr = q0 + kq * 4 + r;
        float sv = (kv <= qr) ? s[j][r] * scale : -1e30f;
        s[j][r] = sv;
        mt[r] = fmaxf(mt[r], sv);
      }
    }
#pragma unroll
    for (int off = 1; off < 16; off <<= 1)
#pragma unroll
      for (int r = 0; r < 4; ++r) mt[r] = fmaxf(mt[r], __shfl_xor(mt[r], off, 64));

    float alpha[4], lt[4];
#pragma unroll
    for (int r = 0; r < 4; ++r) {
      float mn = fmaxf(mrow[r], mt[r]);
      alpha[r] = __expf(mrow[r] - mn);
      mrow[r] = mn;
      lt[r] = 0.f;
    }
#pragma unroll
    for (int j = 0; j < 4; ++j)
#pragma unroll
      for (int r = 0; r < 4; ++r) {
        float p = __expf(s[j][r] - mrow[r]);
        s[j][r] = p;
        lt[r] += p;
      }
#pragma unroll
    for (int off = 1; off < 16; off <<= 1)
#pragma unroll
      for (int r = 0; r < 4; ++r) lt[r] += __shfl_xor(lt[r], off, 64);
#pragma unroll
    for (int r = 0; r < 4; ++r) lrow[r] = lrow[r] * alpha[r] + lt[r];
#pragma unroll
    for (int tt = 0; tt < 8; ++tt)
#pragma unroll
      for (int r = 0; r < 4; ++r) o[tt][r] *= alpha[r];

    // ---- P (C-layout) -> per-wave LDS -> A-layout frags (no barrier: wave-private)
#pragma unroll
    for (int j = 0; j < 4; ++j)
#pragma unroll
      for (int r = 0; r < 4; ++r)
        Plds[w][kq * 4 + r][j * 16 + fr] = f2bf(s[j][r]);

    // ---- PV, V^T fragments straight from global (L2)
#pragma unroll
    for (int st = 0; st < 2; ++st) {
      bf16x8 pf = as_bf16x8(*(const u16x8*)&Plds[w][fr][st * 32 + kq * 8]);
#pragma unroll
      for (int tt = 0; tt < 8; ++tt) {
        bf16x8 vv = as_bf16x8(*(const u16x8*)(vbase + (size_t)(tt * 16 + fr) * S_ + k0 + st * 32 + kq * 8));
        o[tt] = __builtin_amdgcn_mfma_f32_16x16x32_bf16(pf, vv, o[tt], 0, 0, 0);
      }
    }
  }

  float inv[4];
#pragma unroll
  for (int r = 0; r < 4; ++r) inv[r] = 1.0f / lrow[r];
  u16* obase = O + (size_t)(b * S_ + q0) * H_ + (size_t)h * HD;
#pragma unroll
  for (int tt = 0; tt < 8; ++tt)
#pragma unroll
    for (int r = 0; r < 4; ++r)
      obase[(size_t)(kq * 4 + r) * H_ + tt * 16 + fr] = f2bf(o[tt][r] * inv[r]);
}

// ---------------------------------------------------------------------------
extern "C" void kernel_launch(void* const* d_in, const int* in_sizes, int n_in,
                              void* d_out, int out_size, void* d_ws, size_t ws_size,
                              hipStream_t stream) {
  const float* X  = (const float*)d_in[0];
  const float* Wq = (const float*)d_in[2];
  const float* Wk = (const float*)d_in[3];
  const float* Wv = (const float*)d_in[4];
  const float* Wo = (const float*)d_in[5];
  float* out = (float*)d_out;

  // ws (80 MiB): K 8 | Vt 8 | {Xb -> Ob} 32 | Wt 32   (bf16)
  char* ws = (char*)d_ws;
  u16* Kb = (u16*)ws;
  u16* Vt = (u16*)(ws + 8ull  * 1024 * 1024);
  u16* Xb = (u16*)(ws + 16ull * 1024 * 1024);
  u16* Ob = (u16*)(ws + 16ull * 1024 * 1024);
  u16* Wt = (u16*)(ws + 48ull * 1024 * 1024);
  // d_out is 64 MiB fp32; park bf16 Q (32 MiB) and pre-transpose V (8 MiB)
  // there — both dead before the final GEMM overwrites all of d_out.
  u16* Qb = (u16*)d_out;
  u16* Vb = (u16*)((char*)d_out + 32ull * 1024 * 1024);

  dim3 blk(256);

  // X -> bf16 (once; enables global_load_lds staging in all GEMMs)
  conv_bf16<<<dim3((size_t)BS * H_ / 8 / 256), blk, 0, stream>>>(X, Xb);

  // Q = X @ Wq
  conv_transpose_w<<<dim3(64, 64), blk, 0, stream>>>(Wq, Wt, H_, H_);
  gemm_bt_lds<false><<<dim3(32, 32), blk, 0, stream>>>(Xb, Wt, Qb, BS, H_, H_);
  // K = X @ Wk
  conv_transpose_w<<<dim3(64, 16), blk, 0, stream>>>(Wk, Wt, KVD, H_);
  gemm_bt_lds<false><<<dim3(32, 8), blk, 0, stream>>>(Xb, Wt, Kb, BS, KVD, H_);
  // V = X @ Wv
  conv_transpose_w<<<dim3(64, 16), blk, 0, stream>>>(Wv, Wt, KVD, H_);
  gemm_bt_lds<false><<<dim3(32, 8), blk, 0, stream>>>(Xb, Wt, Vb, BS, KVD, H_);
  // RoPE in-place on Q and K
  rope_kernel<<<dim3((BS * 40 * 64) / 256), blk, 0, stream>>>(Qb, Kb);
  // V -> Vt
  transpose_v<<<dim3(S_ / 64, HD / 64, B_ * NKV), blk, 0, stream>>>(Vb, Vt);
  // attention -> Ob  (1D grid: 128 qt x 16 groups, bid%8 == kvh)
  flash_attn<<<dim3(128 * 16), blk, 0, stream>>>(Qb, Kb, Vt, Ob);
  // out = Ob @ Wo  (fp32 out, overwrites all of d_out)
  conv_transpose_w<<<dim3(64, 64), blk, 0, stream>>>(Wo, Wt, H_, H_);
  gemm_bt_lds<true><<<dim3(32, 32), blk, 0, stream>>>(Ob, Wt, out, BS, H_, H_);
}

// Round 4
// 1091.005 us; speedup vs baseline: 1.1963x; 1.1963x over previous
//
#include <hip/hip_runtime.h>
#include <stdint.h>

typedef unsigned short u16;

#define B_   2
#define S_   2048
#define H_   4096
#define NH   32
#define NKV  8
#define HD   128
#define KVD  (NKV * HD)   // 1024
#define BS   (B_ * S_)    // 4096

typedef __bf16 bf16x8 __attribute__((ext_vector_type(8)));
typedef u16    u16x8  __attribute__((ext_vector_type(8)));
typedef u16    u16x4  __attribute__((ext_vector_type(4)));
typedef float  f32x4  __attribute__((ext_vector_type(4)));

__device__ __forceinline__ bf16x8 as_bf16x8(u16x8 v) { return __builtin_bit_cast(bf16x8, v); }

__device__ __forceinline__ float bf2f(u16 u) {
  union { uint32_t u; float f; } v; v.u = ((uint32_t)u) << 16; return v.f;
}
__device__ __forceinline__ u16 f2bf(float f) {
  union { float f; uint32_t u; } v; v.f = f;
  uint32_t r = v.u + 0x7FFFu + ((v.u >> 16) & 1u);
  return (u16)(r >> 16);
}
// hot-path variant: single v_cvt_pk_bf16_f32 instead of 4-op manual RNE
__device__ __forceinline__ u16 f2bf_fast(float f) {
  return __builtin_bit_cast(u16, (__bf16)f);
}

// async global->LDS, 16B per lane; LDS dest must be wave-uniform-base + lane*16
__device__ __forceinline__ void gload_lds16(const void* g, void* l) {
  __builtin_amdgcn_global_load_lds((const __attribute__((address_space(1))) void*)g,
                                   (__attribute__((address_space(3))) void*)l, 16, 0, 0);
}

// ---------------------------------------------------------------------------
// fp32 -> bf16 elementwise (vectorized, 8 elems/thread)
// ---------------------------------------------------------------------------
__global__ __launch_bounds__(256) void conv_bf16(const float* __restrict__ in,
                                                 u16* __restrict__ out) {
  size_t i = ((size_t)blockIdx.x * 256 + threadIdx.x) * 8;
  float4 a = *(const float4*)(in + i);
  float4 b = *(const float4*)(in + i + 4);
  u16x8 h;
  h[0] = f2bf(a.x); h[1] = f2bf(a.y); h[2] = f2bf(a.z); h[3] = f2bf(a.w);
  h[4] = f2bf(b.x); h[5] = f2bf(b.y); h[6] = f2bf(b.z); h[7] = f2bf(b.w);
  *(u16x8*)(out + i) = h;
}

// ---------------------------------------------------------------------------
// Convert + transpose: fp32 in[R][C] -> bf16 out[C][R]; 64x64 tiles.
// ---------------------------------------------------------------------------
__global__ __launch_bounds__(256) void conv_transpose_w(const float* __restrict__ in,
                                                        u16* __restrict__ out,
                                                        int ldi, int ldo) {
  __shared__ u16 tile[64][72];
  int r0 = blockIdx.x * 64, c0 = blockIdx.y * 64;
  int t = threadIdx.x;
  {
    int row = t >> 4, col = (t & 15) * 4;
#pragma unroll
    for (int rep = 0; rep < 4; ++rep) {
      int r = row + rep * 16;
      float4 v = *(const float4*)(in + (size_t)(r0 + r) * ldi + c0 + col);
      u16x4 h;
      h[0] = f2bf(v.x); h[1] = f2bf(v.y); h[2] = f2bf(v.z); h[3] = f2bf(v.w);
      *(u16x4*)&tile[r][col] = h;
    }
  }
  __syncthreads();
  {
    int row = t >> 2, c8 = (t & 3) * 8;
#pragma unroll
    for (int it = 0; it < 2; ++it) {
      int rr = c8 + it * 32;
      u16x8 v;
#pragma unroll
      for (int j = 0; j < 8; ++j) v[j] = tile[rr + j][row];
      *(u16x8*)(out + (size_t)(c0 + row) * ldo + r0 + rr) = v;
    }
  }
}

// ---------------------------------------------------------------------------
// V transpose (bf16): V[b*S_+s][kvh*HD+d] -> Vt[((b*NKV+kvh)*HD + d)*S_ + s]
// ---------------------------------------------------------------------------
__global__ __launch_bounds__(256) void transpose_v(const u16* __restrict__ V,
                                                   u16* __restrict__ Vt) {
  __shared__ u16 tile[64][72];
  int g = blockIdx.z;
  const u16* in = V + (size_t)(g >> 3) * ((size_t)S_ * KVD) + (size_t)(g & 7) * HD;
  u16* out = Vt + (size_t)g * ((size_t)HD * S_);
  int r0 = blockIdx.x * 64, c0 = blockIdx.y * 64;
  int t = threadIdx.x;
  int row = t >> 2, c8 = (t & 3) * 8;
#pragma unroll
  for (int it = 0; it < 2; ++it) {
    int col = c8 + it * 32;
    *(u16x8*)&tile[row][col] = *(const u16x8*)(in + (size_t)(r0 + row) * KVD + c0 + col);
  }
  __syncthreads();
#pragma unroll
  for (int it = 0; it < 2; ++it) {
    int rr = c8 + it * 32;
    u16x8 v;
#pragma unroll
    for (int j = 0; j < 8; ++j) v[j] = tile[rr + j][row];
    *(u16x8*)(out + (size_t)(c0 + row) * S_ + r0 + rr) = v;
  }
}

// ---------------------------------------------------------------------------
// C[M][N] = A[M][K] @ Bt[N][K]^T.  A bf16, C bf16 or fp32.
// m97 structure: 128x128 tile, BK=32, global_load_lds dwordx4 staging,
// 4 waves of 64x64, 16x16x32 bf16 MFMA.
// ---------------------------------------------------------------------------
template <bool C_F32>
__global__ __launch_bounds__(256) void gemm_bt_lds(const u16* __restrict__ A,
                                                   const u16* __restrict__ Bt,
                                                   void* __restrict__ Cp,
                                                   int M, int N, int K) {
  __shared__ __align__(16) u16 lsA[128][32];
  __shared__ __align__(16) u16 lsB[128][32];
  int t = threadIdx.x;
  int lane = t & 63;
  int w = t >> 6;
  int wm = (w >> 1) * 64, wn = (w & 1) * 64;
  int bm = blockIdx.x * 128, bn = blockIdx.y * 128;
  int fr = lane & 15, kq = lane >> 4;
  f32x4 acc[4][4] = {};

  int sr = t >> 2, sc = (t & 3) * 8;
  const u16* Ar0 = A + (size_t)(bm + sr) * K + sc;
  const u16* Ar1 = A + (size_t)(bm + sr + 64) * K + sc;
  const u16* Br0 = Bt + (size_t)(bn + sr) * K + sc;
  const u16* Br1 = Bt + (size_t)(bn + sr + 64) * K + sc;
  u16* lA0 = &lsA[sr][sc];
  u16* lA1 = &lsA[sr + 64][sc];
  u16* lB0 = &lsB[sr][sc];
  u16* lB1 = &lsB[sr + 64][sc];

  for (int k0 = 0; k0 < K; k0 += 32) {
    gload_lds16(Ar0 + k0, lA0);
    gload_lds16(Ar1 + k0, lA1);
    gload_lds16(Br0 + k0, lB0);
    gload_lds16(Br1 + k0, lB1);
    __syncthreads();  // drains vmcnt(0): LDS tiles complete
    bf16x8 af[4], bfr[4];
#pragma unroll
    for (int i = 0; i < 4; ++i) af[i] = as_bf16x8(*(const u16x8*)&lsA[wm + i * 16 + fr][kq * 8]);
#pragma unroll
    for (int j = 0; j < 4; ++j) bfr[j] = as_bf16x8(*(const u16x8*)&lsB[wn + j * 16 + fr][kq * 8]);
#pragma unroll
    for (int i = 0; i < 4; ++i)
#pragma unroll
      for (int j = 0; j < 4; ++j)
        acc[i][j] = __builtin_amdgcn_mfma_f32_16x16x32_bf16(af[i], bfr[j], acc[i][j], 0, 0, 0);
    __syncthreads();  // protect LDS from next-iter staging
  }
#pragma unroll
  for (int i = 0; i < 4; ++i)
#pragma unroll
    for (int j = 0; j < 4; ++j)
#pragma unroll
      for (int r = 0; r < 4; ++r) {
        int row = bm + wm + i * 16 + kq * 4 + r;
        int col = bn + wn + j * 16 + fr;
        if (C_F32) ((float*)Cp)[(size_t)row * N + col] = acc[i][j][r];
        else       ((u16*)Cp)[(size_t)row * N + col] = f2bf(acc[i][j][r]);
      }
}

// ---------------------------------------------------------------------------
// RoPE in-place on bf16 Q [BS][H_] and K [BS][KVD].
// ---------------------------------------------------------------------------
__global__ __launch_bounds__(256) void rope_kernel(u16* __restrict__ Q,
                                                   u16* __restrict__ Kp) {
  int idx = blockIdx.x * 256 + threadIdx.x;  // BS * 40 * 64 total
  int j = idx & 63;
  int rem = idx >> 6;
  int hh = rem % 40;
  int tok = rem / 40;
  float p = (float)(tok % S_);
  float freq = __expf((float)j * (-9.210340371976184f / 64.0f));  // 10000^(-j/64)
  float sn, cs;
  __sincosf(p * freq, &sn, &cs);
  u16* base = (hh < NH) ? (Q + (size_t)tok * H_ + (size_t)hh * HD)
                        : (Kp + (size_t)tok * KVD + (size_t)(hh - NH) * HD);
  float x1 = bf2f(base[j]), x2 = bf2f(base[j + 64]);
  base[j]      = f2bf(x1 * cs - x2 * sn);
  base[j + 64] = f2bf(x2 * cs + x1 * sn);
}

// ---------------------------------------------------------------------------
// Flash attention, causal, GQA(4) — round-2 skeleton (best verified: 296us)
// + this round: V de-swizzled via [128][72] pad (b128 reads, no lo/hi pack),
//   native v_cvt_pk bf16 converts on hot stores, s_setprio around MFMA.
// grid: (S_/32, NKV, B_), 8 waves/block; wave w: head kvh*4+(w&3),
// q-subtile u=(w>>2).  K/V staged in LDS once per iter, shared by 8 waves.
// T14 async-STAGE: tile kt+1 loaded to regs after staging barrier.
// qt reversed so longest (diagonal-heavy) blocks dispatch first.
// ---------------------------------------------------------------------------
__global__ __launch_bounds__(512) void flash_attn(const u16* __restrict__ Q,
                                                  const u16* __restrict__ Kp,
                                                  const u16* __restrict__ Vt,
                                                  u16* __restrict__ O) {
  __shared__ __align__(16) u16 Ks[64 * 128];   // [kv 64][d 128], XOR-swizzled
  __shared__ __align__(16) u16 Vs[128][72];    // [d 128][kv 64+8 pad], linear
  __shared__ u16 Plds[8][16][72];              // per-wave P tile, +8 pad
  int qt = (gridDim.x - 1) - blockIdx.x;       // longest blocks first
  int kvh = blockIdx.y, b = blockIdx.z;
  int t = threadIdx.x, lane = t & 63, w = t >> 6;
  int h = kvh * 4 + (w & 3);                   // this wave's head
  int u = w >> 2;                              // q-subtile within block
  int fr = lane & 15, kq = lane >> 4;
  int q0 = qt * 32 + u * 16;                   // this wave's 16 q-rows

  const u16* qbase = Q + (size_t)(b * S_ + q0 + fr) * H_ + (size_t)h * HD;
  bf16x8 qf[4];
#pragma unroll
  for (int kk = 0; kk < 4; ++kk) qf[kk] = as_bf16x8(*(const u16x8*)(qbase + kk * 32 + kq * 8));

  f32x4 o[8] = {};
  float mrow[4] = {-1e30f, -1e30f, -1e30f, -1e30f};
  float lrow[4] = {0.f, 0.f, 0.f, 0.f};

  const u16* kbase = Kp + (size_t)(b * S_) * KVD + (size_t)kvh * HD;
  const u16* vbase = Vt + (size_t)(b * NKV + kvh) * ((size_t)HD * S_);
  const float scale = 0.08838834764831845f;  // 1/sqrt(128)

  // staging geometry (512 threads): K 64x256B in 16B chunks (2/thread),
  // V 128x128B in 16B chunks (2/thread), written straight to padded rows.
  int krow0 = t >> 4, kc = t & 15;             // K: idx = ps*512 + t
  int vrow0 = t >> 3, vc = t & 7;              // V: idx = ps*512 + t

  int niter = (qt * 32 + 31) / 64 + 1;

  // ---- prologue: load tile 0 into regs
  u16x8 kreg[2], vreg[2];
#pragma unroll
  for (int ps = 0; ps < 2; ++ps) {
    int row = krow0 + ps * 32;
    kreg[ps] = *(const u16x8*)(kbase + (size_t)row * KVD + kc * 8);
    int vrow = vrow0 + ps * 64;
    vreg[ps] = *(const u16x8*)(vbase + (size_t)vrow * S_ + vc * 8);
  }

  for (int kt = 0; kt < niter; ++kt) {
    int k0 = kt * 64;
    if (kt) __syncthreads();   // all waves done reading LDS tile kt-1
    // ---- write staged regs -> LDS (K: 16B chunks, chunk' = c ^ (row&15))
#pragma unroll
    for (int ps = 0; ps < 2; ++ps) {
      int row = krow0 + ps * 32;
      *(u16x8*)&Ks[row * 128 + ((kc ^ row) & 15) * 8] = kreg[ps];
      int vrow = vrow0 + ps * 64;
      *(u16x8*)&Vs[vrow][vc * 8] = vreg[ps];
    }
    __syncthreads();           // tile kt visible to all waves
    // ---- T14: issue loads for tile kt+1 (consumed next iteration)
    if (kt + 1 < niter) {
      int k1 = k0 + 64;
#pragma unroll
      for (int ps = 0; ps < 2; ++ps) {
        int row = krow0 + ps * 32;
        kreg[ps] = *(const u16x8*)(kbase + (size_t)(k1 + row) * KVD + kc * 8);
        int vrow = vrow0 + ps * 64;
        vreg[ps] = *(const u16x8*)(vbase + (size_t)vrow * S_ + k1 + vc * 8);
      }
    }

    // ---- S = Q K^T from LDS
    f32x4 s[4] = {};
    __builtin_amdgcn_s_setprio(1);
#pragma unroll
    for (int kk = 0; kk < 4; ++kk) {
#pragma unroll
      for (int j = 0; j < 4; ++j) {
        bf16x8 kf = as_bf16x8(*(const u16x8*)&Ks[(j * 16 + fr) * 128 + (((kk * 4 + kq) ^ fr) & 15) * 8]);
        s[j] = __builtin_amdgcn_mfma_f32_16x16x32_bf16(qf[kk], kf, s[j], 0, 0, 0);
      }
    }
    __builtin_amdgcn_s_setprio(0);
    // ---- scale + causal mask + row max
    float mt[4] = {-1e30f, -1e30f, -1e30f, -1e30f};
#pragma unroll
    for (int j = 0; j < 4; ++j) {
      int kv = k0 + j * 16 + fr;
#pragma unroll
      for (int r = 0; r < 4; ++r) {
        int qr = q0 + kq * 4 + r;
        float sv = (kv <= qr) ? s[j][r] * scale : -1e30f;
        s[j][r] = sv;
        mt[r] = fmaxf(mt[r], sv);
      }
    }
#pragma unroll
    for (int off = 1; off < 16; off <<= 1)
#pragma unroll
      for (int r = 0; r < 4; ++r) mt[r] = fmaxf(mt[r], __shfl_xor(mt[r], off, 64));

    float alpha[4], lt[4];
#pragma unroll
    for (int r = 0; r < 4; ++r) {
      float mn = fmaxf(mrow[r], mt[r]);
      alpha[r] = __expf(mrow[r] - mn);
      mrow[r] = mn;
      lt[r] = 0.f;
    }
#pragma unroll
    for (int j = 0; j < 4; ++j)
#pragma unroll
      for (int r = 0; r < 4; ++r) {
        float p = __expf(s[j][r] - mrow[r]);
        s[j][r] = p;
        lt[r] += p;
      }
#pragma unroll
    for (int off = 1; off < 16; off <<= 1)
#pragma unroll
      for (int r = 0; r < 4; ++r) lt[r] += __shfl_xor(lt[r], off, 64);
#pragma unroll
    for (int r = 0; r < 4; ++r) lrow[r] = lrow[r] * alpha[r] + lt[r];
#pragma unroll
    for (int tt = 0; tt < 8; ++tt)
#pragma unroll
      for (int r = 0; r < 4; ++r) o[tt][r] *= alpha[r];

    // ---- P (C-layout) -> per-wave LDS -> A-layout frags
#pragma unroll
    for (int j = 0; j < 4; ++j)
#pragma unroll
      for (int r = 0; r < 4; ++r)
        Plds[w][kq * 4 + r][j * 16 + fr] = f2bf_fast(s[j][r]);

#pragma unroll
    for (int st = 0; st < 2; ++st) {
      bf16x8 pf = as_bf16x8(*(const u16x8*)&Plds[w][fr][st * 32 + kq * 8]);
      __builtin_amdgcn_s_setprio(1);
#pragma unroll
      for (int tt = 0; tt < 8; ++tt) {
        bf16x8 vv = as_bf16x8(*(const u16x8*)&Vs[tt * 16 + fr][st * 32 + kq * 8]);
        o[tt] = __builtin_amdgcn_mfma_f32_16x16x32_bf16(pf, vv, o[tt], 0, 0, 0);
      }
      __builtin_amdgcn_s_setprio(0);
    }
  }

  float inv[4];
#pragma unroll
  for (int r = 0; r < 4; ++r) inv[r] = 1.0f / lrow[r];
  u16* obase = O + (size_t)(b * S_ + q0) * H_ + (size_t)h * HD;
#pragma unroll
  for (int tt = 0; tt < 8; ++tt)
#pragma unroll
    for (int r = 0; r < 4; ++r)
      obase[(size_t)(kq * 4 + r) * H_ + tt * 16 + fr] = f2bf_fast(o[tt][r] * inv[r]);
}

// ---------------------------------------------------------------------------
extern "C" void kernel_launch(void* const* d_in, const int* in_sizes, int n_in,
                              void* d_out, int out_size, void* d_ws, size_t ws_size,
                              hipStream_t stream) {
  const float* X  = (const float*)d_in[0];
  const float* Wq = (const float*)d_in[2];
  const float* Wk = (const float*)d_in[3];
  const float* Wv = (const float*)d_in[4];
  const float* Wo = (const float*)d_in[5];
  float* out = (float*)d_out;

  // ws (80 MiB): K 8 | Vt 8 | {Xb -> Ob} 32 | Wt 32   (bf16)
  char* ws = (char*)d_ws;
  u16* Kb = (u16*)ws;
  u16* Vt = (u16*)(ws + 8ull  * 1024 * 1024);
  u16* Xb = (u16*)(ws + 16ull * 1024 * 1024);
  u16* Ob = (u16*)(ws + 16ull * 1024 * 1024);
  u16* Wt = (u16*)(ws + 48ull * 1024 * 1024);
  // d_out is 64 MiB fp32; park bf16 Q (32 MiB) and pre-transpose V (8 MiB)
  // there — both dead before the final GEMM overwrites all of d_out.
  u16* Qb = (u16*)d_out;
  u16* Vb = (u16*)((char*)d_out + 32ull * 1024 * 1024);

  dim3 blk(256);
  dim3 blk8(512);

  // X -> bf16 (once; enables global_load_lds staging in all GEMMs)
  conv_bf16<<<dim3((size_t)BS * H_ / 8 / 256), blk, 0, stream>>>(X, Xb);

  // Q = X @ Wq
  conv_transpose_w<<<dim3(64, 64), blk, 0, stream>>>(Wq, Wt, H_, H_);
  gemm_bt_lds<false><<<dim3(32, 32), blk, 0, stream>>>(Xb, Wt, Qb, BS, H_, H_);
  // K = X @ Wk
  conv_transpose_w<<<dim3(64, 16), blk, 0, stream>>>(Wk, Wt, KVD, H_);
  gemm_bt_lds<false><<<dim3(32, 8), blk, 0, stream>>>(Xb, Wt, Kb, BS, KVD, H_);
  // V = X @ Wv
  conv_transpose_w<<<dim3(64, 16), blk, 0, stream>>>(Wv, Wt, KVD, H_);
  gemm_bt_lds<false><<<dim3(32, 8), blk, 0, stream>>>(Xb, Wt, Vb, BS, KVD, H_);
  // RoPE in-place on Q and K
  rope_kernel<<<dim3((BS * 40 * 64) / 256), blk, 0, stream>>>(Qb, Kb);
  // V -> Vt
  transpose_v<<<dim3(S_ / 64, HD / 64, B_ * NKV), blk, 0, stream>>>(Vb, Vt);
  // attention -> Ob
  flash_attn<<<dim3(S_ / 32, NKV, B_), blk8, 0, stream>>>(Qb, Kb, Vt, Ob);
  // out = Ob @ Wo  (fp32 out, overwrites all of d_out)
  conv_transpose_w<<<dim3(64, 64), blk, 0, stream>>>(Wo, Wt, H_, H_);
  gemm_bt_lds<true><<<dim3(32, 32), blk, 0, stream>>>(Ob, Wt, out, BS, H_, H_);
}

// Round 5
// 928.996 us; speedup vs baseline: 1.4049x; 1.1744x over previous
//
#include <hip/hip_runtime.h>
#include <stdint.h>

typedef unsigned short u16;

#define B_   2
#define S_   2048
#define H_   4096
#define NH   32
#define NKV  8
#define HD   128
#define KVD  (NKV * HD)   // 1024
#define BS   (B_ * S_)    // 4096
#define QS   6144         // QKV row stride (Q 0..4095 | K 4096..5119 | V 5120..6143)
#define KOFF 4096
#define VOFF 5120

typedef __bf16 bf16x8 __attribute__((ext_vector_type(8)));
typedef u16    u16x8  __attribute__((ext_vector_type(8)));
typedef u16    u16x4  __attribute__((ext_vector_type(4)));
typedef float  f32x4  __attribute__((ext_vector_type(4)));

__device__ __forceinline__ bf16x8 as_bf16x8(u16x8 v) { return __builtin_bit_cast(bf16x8, v); }

__device__ __forceinline__ float bf2f(u16 u) {
  union { uint32_t u; float f; } v; v.u = ((uint32_t)u) << 16; return v.f;
}
__device__ __forceinline__ u16 f2bf(float f) {
  union { float f; uint32_t u; } v; v.f = f;
  uint32_t r = v.u + 0x7FFFu + ((v.u >> 16) & 1u);
  return (u16)(r >> 16);
}
// hot-path variant: single v_cvt_pk_bf16_f32 instead of 4-op manual RNE
__device__ __forceinline__ u16 f2bf_fast(float f) {
  return __builtin_bit_cast(u16, (__bf16)f);
}

// async global->LDS, 16B per lane; LDS dest must be wave-uniform-base + lane*16
__device__ __forceinline__ void gload_lds16(const void* g, void* l) {
  __builtin_amdgcn_global_load_lds((const __attribute__((address_space(1))) void*)g,
                                   (__attribute__((address_space(3))) void*)l, 16, 0, 0);
}

// ---------------------------------------------------------------------------
// fp32 -> bf16 elementwise (vectorized, 8 elems/thread)
// ---------------------------------------------------------------------------
__global__ __launch_bounds__(256) void conv_bf16(const float* __restrict__ in,
                                                 u16* __restrict__ out) {
  size_t i = ((size_t)blockIdx.x * 256 + threadIdx.x) * 8;
  float4 a = *(const float4*)(in + i);
  float4 b = *(const float4*)(in + i + 4);
  u16x8 h;
  h[0] = f2bf(a.x); h[1] = f2bf(a.y); h[2] = f2bf(a.z); h[3] = f2bf(a.w);
  h[4] = f2bf(b.x); h[5] = f2bf(b.y); h[6] = f2bf(b.z); h[7] = f2bf(b.w);
  *(u16x8*)(out + i) = h;
}

// ---------------------------------------------------------------------------
// Convert + transpose: fp32 in[R][C] -> bf16 out[C][R]; 64x64 tiles.
// ---------------------------------------------------------------------------
__global__ __launch_bounds__(256) void conv_transpose_w(const float* __restrict__ in,
                                                        u16* __restrict__ out,
                                                        int ldi, int ldo) {
  __shared__ u16 tile[64][72];
  int r0 = blockIdx.x * 64, c0 = blockIdx.y * 64;
  int t = threadIdx.x;
  {
    int row = t >> 4, col = (t & 15) * 4;
#pragma unroll
    for (int rep = 0; rep < 4; ++rep) {
      int r = row + rep * 16;
      float4 v = *(const float4*)(in + (size_t)(r0 + r) * ldi + c0 + col);
      u16x4 h;
      h[0] = f2bf(v.x); h[1] = f2bf(v.y); h[2] = f2bf(v.z); h[3] = f2bf(v.w);
      *(u16x4*)&tile[r][col] = h;
    }
  }
  __syncthreads();
  {
    int row = t >> 2, c8 = (t & 3) * 8;
#pragma unroll
    for (int it = 0; it < 2; ++it) {
      int rr = c8 + it * 32;
      u16x8 v;
#pragma unroll
      for (int j = 0; j < 8; ++j) v[j] = tile[rr + j][row];
      *(u16x8*)(out + (size_t)(c0 + row) * ldo + r0 + rr) = v;
    }
  }
}

// ---------------------------------------------------------------------------
// V transpose (bf16): QKV[b*S_+s][VOFF+kvh*HD+d] -> Vt[((b*NKV+kvh)*HD+d)*S_+s]
// ---------------------------------------------------------------------------
__global__ __launch_bounds__(256) void transpose_v(const u16* __restrict__ QKV,
                                                   u16* __restrict__ Vt) {
  __shared__ u16 tile[64][72];
  int g = blockIdx.z;
  const u16* in = QKV + (size_t)(g >> 3) * ((size_t)S_ * QS) + VOFF + (size_t)(g & 7) * HD;
  u16* out = Vt + (size_t)g * ((size_t)HD * S_);
  int r0 = blockIdx.x * 64, c0 = blockIdx.y * 64;
  int t = threadIdx.x;
  int row = t >> 2, c8 = (t & 3) * 8;
#pragma unroll
  for (int it = 0; it < 2; ++it) {
    int col = c8 + it * 32;
    *(u16x8*)&tile[row][col] = *(const u16x8*)(in + (size_t)(r0 + row) * QS + c0 + col);
  }
  __syncthreads();
#pragma unroll
  for (int it = 0; it < 2; ++it) {
    int rr = c8 + it * 32;
    u16x8 v;
#pragma unroll
    for (int j = 0; j < 8; ++j) v[j] = tile[rr + j][row];
    *(u16x8*)(out + (size_t)(c0 + row) * S_ + r0 + rr) = v;
  }
}

// ---------------------------------------------------------------------------
// C[M][N] = A[M][K] @ Bt[N][K]^T.  A bf16, C bf16 or fp32.
// m97 structure: 128x128 tile, BK=32, global_load_lds dwordx4 staging,
// 4 waves of 64x64, 16x16x32 bf16 MFMA.
// ---------------------------------------------------------------------------
template <bool C_F32>
__global__ __launch_bounds__(256) void gemm_bt_lds(const u16* __restrict__ A,
                                                   const u16* __restrict__ Bt,
                                                   void* __restrict__ Cp,
                                                   int M, int N, int K) {
  __shared__ __align__(16) u16 lsA[128][32];
  __shared__ __align__(16) u16 lsB[128][32];
  int t = threadIdx.x;
  int lane = t & 63;
  int w = t >> 6;
  int wm = (w >> 1) * 64, wn = (w & 1) * 64;
  int bm = blockIdx.x * 128, bn = blockIdx.y * 128;
  int fr = lane & 15, kq = lane >> 4;
  f32x4 acc[4][4] = {};

  int sr = t >> 2, sc = (t & 3) * 8;
  const u16* Ar0 = A + (size_t)(bm + sr) * K + sc;
  const u16* Ar1 = A + (size_t)(bm + sr + 64) * K + sc;
  const u16* Br0 = Bt + (size_t)(bn + sr) * K + sc;
  const u16* Br1 = Bt + (size_t)(bn + sr + 64) * K + sc;
  u16* lA0 = &lsA[sr][sc];
  u16* lA1 = &lsA[sr + 64][sc];
  u16* lB0 = &lsB[sr][sc];
  u16* lB1 = &lsB[sr + 64][sc];

  for (int k0 = 0; k0 < K; k0 += 32) {
    gload_lds16(Ar0 + k0, lA0);
    gload_lds16(Ar1 + k0, lA1);
    gload_lds16(Br0 + k0, lB0);
    gload_lds16(Br1 + k0, lB1);
    __syncthreads();  // drains vmcnt(0): LDS tiles complete
    bf16x8 af[4], bfr[4];
#pragma unroll
    for (int i = 0; i < 4; ++i) af[i] = as_bf16x8(*(const u16x8*)&lsA[wm + i * 16 + fr][kq * 8]);
#pragma unroll
    for (int j = 0; j < 4; ++j) bfr[j] = as_bf16x8(*(const u16x8*)&lsB[wn + j * 16 + fr][kq * 8]);
#pragma unroll
    for (int i = 0; i < 4; ++i)
#pragma unroll
      for (int j = 0; j < 4; ++j)
        acc[i][j] = __builtin_amdgcn_mfma_f32_16x16x32_bf16(af[i], bfr[j], acc[i][j], 0, 0, 0);
    __syncthreads();  // protect LDS from next-iter staging
  }
#pragma unroll
  for (int i = 0; i < 4; ++i)
#pragma unroll
    for (int j = 0; j < 4; ++j)
#pragma unroll
      for (int r = 0; r < 4; ++r) {
        int row = bm + wm + i * 16 + kq * 4 + r;
        int col = bn + wn + j * 16 + fr;
        if (C_F32) ((float*)Cp)[(size_t)row * N + col] = acc[i][j][r];
        else       ((u16*)Cp)[(size_t)row * N + col] = f2bf(acc[i][j][r]);
      }
}

// ---------------------------------------------------------------------------
// Fused QKV projection: C[4096][6144] = Xb @ [Wq | Wk | Wv].
// Same m97 body as gemm_bt_lds; B-matrix selected per block (uniform branch).
// 32x48 = 1536 blocks = 6/CU (fixes K/V-proj's 1-block/CU occupancy hole).
// ---------------------------------------------------------------------------
__global__ __launch_bounds__(256) void gemm_qkv(const u16* __restrict__ A,
                                                const u16* __restrict__ Wtq,
                                                const u16* __restrict__ Wtk,
                                                const u16* __restrict__ Wtv,
                                                u16* __restrict__ C) {
  const int K = H_;
  __shared__ __align__(16) u16 lsA[128][32];
  __shared__ __align__(16) u16 lsB[128][32];
  int t = threadIdx.x;
  int lane = t & 63;
  int w = t >> 6;
  int wm = (w >> 1) * 64, wn = (w & 1) * 64;
  int bm = blockIdx.x * 128;
  int by = blockIdx.y;                 // 0..47
  const u16* Bt; int bnl;
  if (by < 32)      { Bt = Wtq; bnl = by * 128; }
  else if (by < 40) { Bt = Wtk; bnl = (by - 32) * 128; }
  else              { Bt = Wtv; bnl = (by - 40) * 128; }
  int bn = by * 128;                   // global col in QKV space
  int fr = lane & 15, kq = lane >> 4;
  f32x4 acc[4][4] = {};

  int sr = t >> 2, sc = (t & 3) * 8;
  const u16* Ar0 = A + (size_t)(bm + sr) * K + sc;
  const u16* Ar1 = Ar0 + (size_t)64 * K;
  const u16* Br0 = Bt + (size_t)(bnl + sr) * K + sc;
  const u16* Br1 = Br0 + (size_t)64 * K;
  u16* lA0 = &lsA[sr][sc];
  u16* lA1 = &lsA[sr + 64][sc];
  u16* lB0 = &lsB[sr][sc];
  u16* lB1 = &lsB[sr + 64][sc];

  for (int k0 = 0; k0 < K; k0 += 32) {
    gload_lds16(Ar0 + k0, lA0);
    gload_lds16(Ar1 + k0, lA1);
    gload_lds16(Br0 + k0, lB0);
    gload_lds16(Br1 + k0, lB1);
    __syncthreads();
    bf16x8 af[4], bfr[4];
#pragma unroll
    for (int i = 0; i < 4; ++i) af[i] = as_bf16x8(*(const u16x8*)&lsA[wm + i * 16 + fr][kq * 8]);
#pragma unroll
    for (int j = 0; j < 4; ++j) bfr[j] = as_bf16x8(*(const u16x8*)&lsB[wn + j * 16 + fr][kq * 8]);
#pragma unroll
    for (int i = 0; i < 4; ++i)
#pragma unroll
      for (int j = 0; j < 4; ++j)
        acc[i][j] = __builtin_amdgcn_mfma_f32_16x16x32_bf16(af[i], bfr[j], acc[i][j], 0, 0, 0);
    __syncthreads();
  }
#pragma unroll
  for (int i = 0; i < 4; ++i)
#pragma unroll
    for (int j = 0; j < 4; ++j)
#pragma unroll
      for (int r = 0; r < 4; ++r) {
        int row = bm + wm + i * 16 + kq * 4 + r;
        int col = bn + wn + j * 16 + fr;
        C[(size_t)row * QS + col] = f2bf(acc[i][j][r]);
      }
}

// ---------------------------------------------------------------------------
// RoPE in-place on QKV (Q heads hh=0..31 at col hh*128; K heads hh=32..39
// at col KOFF+(hh-32)*128 == hh*128 — unified addressing).
// ---------------------------------------------------------------------------
__global__ __launch_bounds__(256) void rope_kernel(u16* __restrict__ QKV) {
  int idx = blockIdx.x * 256 + threadIdx.x;  // BS * 40 * 64 total
  int j = idx & 63;
  int rem = idx >> 6;
  int hh = rem % 40;
  int tok = rem / 40;
  float p = (float)(tok % S_);
  float freq = __expf((float)j * (-9.210340371976184f / 64.0f));  // 10000^(-j/64)
  float sn, cs;
  __sincosf(p * freq, &sn, &cs);
  u16* base = QKV + (size_t)tok * QS + (size_t)hh * HD;
  float x1 = bf2f(base[j]), x2 = bf2f(base[j + 64]);
  base[j]      = f2bf(x1 * cs - x2 * sn);
  base[j + 64] = f2bf(x2 * cs + x1 * sn);
}

// ---------------------------------------------------------------------------
// Flash attention, causal, GQA(4) — unchanged structure (control), Q/K now
// read from QKV (stride QS).
// grid: (S_/32, NKV, B_), 8 waves/block; wave w: head kvh*4+(w&3),
// q-subtile u=(w>>2).  K/V staged in LDS once per iter, shared by 8 waves.
// T14 async-STAGE: tile kt+1 loaded to regs after staging barrier.
// qt reversed so longest (diagonal-heavy) blocks dispatch first.
// ---------------------------------------------------------------------------
__global__ __launch_bounds__(512) void flash_attn(const u16* __restrict__ QKV,
                                                  const u16* __restrict__ Vt,
                                                  u16* __restrict__ O) {
  __shared__ __align__(16) u16 Ks[64 * 128];   // [kv 64][d 128], XOR-swizzled
  __shared__ __align__(16) u16 Vs[128][72];    // [d 128][kv 64+8 pad], linear
  __shared__ u16 Plds[8][16][72];              // per-wave P tile, +8 pad
  int qt = (gridDim.x - 1) - blockIdx.x;       // longest blocks first
  int kvh = blockIdx.y, b = blockIdx.z;
  int t = threadIdx.x, lane = t & 63, w = t >> 6;
  int h = kvh * 4 + (w & 3);                   // this wave's head
  int u = w >> 2;                              // q-subtile within block
  int fr = lane & 15, kq = lane >> 4;
  int q0 = qt * 32 + u * 16;                   // this wave's 16 q-rows

  const u16* qbase = QKV + (size_t)(b * S_ + q0 + fr) * QS + (size_t)h * HD;
  bf16x8 qf[4];
#pragma unroll
  for (int kk = 0; kk < 4; ++kk) qf[kk] = as_bf16x8(*(const u16x8*)(qbase + kk * 32 + kq * 8));

  f32x4 o[8] = {};
  float mrow[4] = {-1e30f, -1e30f, -1e30f, -1e30f};
  float lrow[4] = {0.f, 0.f, 0.f, 0.f};

  const u16* kbase = QKV + (size_t)(b * S_) * QS + KOFF + (size_t)kvh * HD;
  const u16* vbase = Vt + (size_t)(b * NKV + kvh) * ((size_t)HD * S_);
  const float scale = 0.08838834764831845f;  // 1/sqrt(128)

  // staging geometry (512 threads): K 64x256B in 16B chunks (2/thread),
  // V 128x128B in 16B chunks (2/thread), written straight to padded rows.
  int krow0 = t >> 4, kc = t & 15;             // K: idx = ps*512 + t
  int vrow0 = t >> 3, vc = t & 7;              // V: idx = ps*512 + t

  int niter = (qt * 32 + 31) / 64 + 1;

  // ---- prologue: load tile 0 into regs
  u16x8 kreg[2], vreg[2];
#pragma unroll
  for (int ps = 0; ps < 2; ++ps) {
    int row = krow0 + ps * 32;
    kreg[ps] = *(const u16x8*)(kbase + (size_t)row * QS + kc * 8);
    int vrow = vrow0 + ps * 64;
    vreg[ps] = *(const u16x8*)(vbase + (size_t)vrow * S_ + vc * 8);
  }

  for (int kt = 0; kt < niter; ++kt) {
    int k0 = kt * 64;
    if (kt) __syncthreads();   // all waves done reading LDS tile kt-1
    // ---- write staged regs -> LDS (K: 16B chunks, chunk' = c ^ (row&15))
#pragma unroll
    for (int ps = 0; ps < 2; ++ps) {
      int row = krow0 + ps * 32;
      *(u16x8*)&Ks[row * 128 + ((kc ^ row) & 15) * 8] = kreg[ps];
      int vrow = vrow0 + ps * 64;
      *(u16x8*)&Vs[vrow][vc * 8] = vreg[ps];
    }
    __syncthreads();           // tile kt visible to all waves
    // ---- T14: issue loads for tile kt+1 (consumed next iteration)
    if (kt + 1 < niter) {
      int k1 = k0 + 64;
#pragma unroll
      for (int ps = 0; ps < 2; ++ps) {
        int row = krow0 + ps * 32;
        kreg[ps] = *(const u16x8*)(kbase + (size_t)(k1 + row) * QS + kc * 8);
        int vrow = vrow0 + ps * 64;
        vreg[ps] = *(const u16x8*)(vbase + (size_t)vrow * S_ + k1 + vc * 8);
      }
    }

    // ---- S = Q K^T from LDS
    f32x4 s[4] = {};
    __builtin_amdgcn_s_setprio(1);
#pragma unroll
    for (int kk = 0; kk < 4; ++kk) {
#pragma unroll
      for (int j = 0; j < 4; ++j) {
        bf16x8 kf = as_bf16x8(*(const u16x8*)&Ks[(j * 16 + fr) * 128 + (((kk * 4 + kq) ^ fr) & 15) * 8]);
        s[j] = __builtin_amdgcn_mfma_f32_16x16x32_bf16(qf[kk], kf, s[j], 0, 0, 0);
      }
    }
    __builtin_amdgcn_s_setprio(0);
    // ---- scale + causal mask + row max
    float mt[4] = {-1e30f, -1e30f, -1e30f, -1e30f};
#pragma unroll
    for (int j = 0; j < 4; ++j) {
      int kv = k0 + j * 16 + fr;
#pragma unroll
      for (int r = 0; r < 4; ++r) {
        int qr = q0 + kq * 4 + r;
        float sv = (kv <= qr) ? s[j][r] * scale : -1e30f;
        s[j][r] = sv;
        mt[r] = fmaxf(mt[r], sv);
      }
    }
#pragma unroll
    for (int off = 1; off < 16; off <<= 1)
#pragma unroll
      for (int r = 0; r < 4; ++r) mt[r] = fmaxf(mt[r], __shfl_xor(mt[r], off, 64));

    float alpha[4], lt[4];
#pragma unroll
    for (int r = 0; r < 4; ++r) {
      float mn = fmaxf(mrow[r], mt[r]);
      alpha[r] = __expf(mrow[r] - mn);
      mrow[r] = mn;
      lt[r] = 0.f;
    }
#pragma unroll
    for (int j = 0; j < 4; ++j)
#pragma unroll
      for (int r = 0; r < 4; ++r) {
        float p = __expf(s[j][r] - mrow[r]);
        s[j][r] = p;
        lt[r] += p;
      }
#pragma unroll
    for (int off = 1; off < 16; off <<= 1)
#pragma unroll
      for (int r = 0; r < 4; ++r) lt[r] += __shfl_xor(lt[r], off, 64);
#pragma unroll
    for (int r = 0; r < 4; ++r) lrow[r] = lrow[r] * alpha[r] + lt[r];
#pragma unroll
    for (int tt = 0; tt < 8; ++tt)
#pragma unroll
      for (int r = 0; r < 4; ++r) o[tt][r] *= alpha[r];

    // ---- P (C-layout) -> per-wave LDS -> A-layout frags
#pragma unroll
    for (int j = 0; j < 4; ++j)
#pragma unroll
      for (int r = 0; r < 4; ++r)
        Plds[w][kq * 4 + r][j * 16 + fr] = f2bf_fast(s[j][r]);

#pragma unroll
    for (int st = 0; st < 2; ++st) {
      bf16x8 pf = as_bf16x8(*(const u16x8*)&Plds[w][fr][st * 32 + kq * 8]);
      __builtin_amdgcn_s_setprio(1);
#pragma unroll
      for (int tt = 0; tt < 8; ++tt) {
        bf16x8 vv = as_bf16x8(*(const u16x8*)&Vs[tt * 16 + fr][st * 32 + kq * 8]);
        o[tt] = __builtin_amdgcn_mfma_f32_16x16x32_bf16(pf, vv, o[tt], 0, 0, 0);
      }
      __builtin_amdgcn_s_setprio(0);
    }
  }

  float inv[4];
#pragma unroll
  for (int r = 0; r < 4; ++r) inv[r] = 1.0f / lrow[r];
  u16* obase = O + (size_t)(b * S_ + q0) * H_ + (size_t)h * HD;
#pragma unroll
  for (int tt = 0; tt < 8; ++tt)
#pragma unroll
    for (int r = 0; r < 4; ++r)
      obase[(size_t)(kq * 4 + r) * H_ + tt * 16 + fr] = f2bf_fast(o[tt][r] * inv[r]);
}

// ---------------------------------------------------------------------------
extern "C" void kernel_launch(void* const* d_in, const int* in_sizes, int n_in,
                              void* d_out, int out_size, void* d_ws, size_t ws_size,
                              hipStream_t stream) {
  const float* X  = (const float*)d_in[0];
  const float* Wq = (const float*)d_in[2];
  const float* Wk = (const float*)d_in[3];
  const float* Wv = (const float*)d_in[4];
  const float* Wo = (const float*)d_in[5];
  float* out = (float*)d_out;

  // ws (80 MiB): Wtk 8 | Vt 8 | {Xb -> Ob} 32 | Wtq 32   (bf16)
  // Xb dead after QKV GEMM; Ob first written by flash_attn.
  char* ws = (char*)d_ws;
  u16* Wtk = (u16*)ws;
  u16* Vt  = (u16*)(ws + 8ull  * 1024 * 1024);
  u16* Xb  = (u16*)(ws + 16ull * 1024 * 1024);
  u16* Ob  = (u16*)(ws + 16ull * 1024 * 1024);
  u16* Wtq = (u16*)(ws + 48ull * 1024 * 1024);
  // d_out (64 MiB fp32): QKV bf16 [4096][6144] = 48 MiB | Wtv 8 MiB | spare.
  // Wtv dead after QKV GEMM; QKV dead after flash_attn; final GEMM
  // overwrites all of d_out.
  u16* QKV = (u16*)d_out;
  u16* Wtv = (u16*)((char*)d_out + 48ull * 1024 * 1024);

  dim3 blk(256);
  dim3 blk8(512);

  // X -> bf16 (once; enables global_load_lds staging in all GEMMs)
  conv_bf16<<<dim3((size_t)BS * H_ / 8 / 256), blk, 0, stream>>>(X, Xb);

  // weight transposes
  conv_transpose_w<<<dim3(64, 64), blk, 0, stream>>>(Wq, Wtq, H_, H_);
  conv_transpose_w<<<dim3(64, 16), blk, 0, stream>>>(Wk, Wtk, KVD, H_);
  conv_transpose_w<<<dim3(64, 16), blk, 0, stream>>>(Wv, Wtv, KVD, H_);

  // QKV = Xb @ [Wq | Wk | Wv]  (one dispatch, 1536 blocks = 6/CU)
  gemm_qkv<<<dim3(32, 48), blk, 0, stream>>>(Xb, Wtq, Wtk, Wtv, QKV);

  // RoPE in-place on Q and K (unified QKV addressing)
  rope_kernel<<<dim3((BS * 40 * 64) / 256), blk, 0, stream>>>(QKV);
  // V -> Vt
  transpose_v<<<dim3(S_ / 64, HD / 64, B_ * NKV), blk, 0, stream>>>(QKV, Vt);
  // attention -> Ob
  flash_attn<<<dim3(S_ / 32, NKV, B_), blk8, 0, stream>>>(QKV, Vt, Ob);
  // out = Ob @ Wo  (fp32 out, overwrites all of d_out)
  conv_transpose_w<<<dim3(64, 64), blk, 0, stream>>>(Wo, Wtq, H_, H_);
  gemm_bt_lds<true><<<dim3(32, 32), blk, 0, stream>>>(Ob, Wtq, out, BS, H_, H_);
}